// Round 4
// baseline (217.593 us; speedup 1.0000x reference)
//
#include <hip/hip_runtime.h>
#include <hip/hip_bf16.h>
#include <stdint.h>

#define D_MODEL 1024
#define NH 16
#define DK 64
#define S_LEN 2048

typedef __attribute__((ext_vector_type(8))) __bf16 bf16x8;
typedef __attribute__((ext_vector_type(4))) float f32x4;

#define GLOBAL_AS __attribute__((address_space(1)))
#define LDS_AS    __attribute__((address_space(3)))

// async global->LDS DMA, 16B per lane; lane i's 16B lands at ldsbase + i*16.
__device__ __forceinline__ void async16(const ushort* g, ushort* l) {
    __builtin_amdgcn_global_load_lds(
        (const GLOBAL_AS uint32_t*)(uintptr_t)(const void*)g,
        (LDS_AS uint32_t*)(uint32_t)(uintptr_t)(void*)l,
        16, 0, 0);
}

// raw barrier with fine-grained vmcnt: waits only until <=N VMEM ops outstanding
// (prefetch issued this iter stays in flight across the barrier).
template <int N>
__device__ __forceinline__ void pipe_barrier() {
    asm volatile("s_waitcnt vmcnt(%0)\n\ts_barrier" :: "n"(N) : "memory");
}

__device__ __forceinline__ float fast_exp2(float x) {
    float r;
    asm("v_exp_f32 %0, %1" : "=v"(r) : "v"(x));   // D = 2^S0
    return r;
}

// fp32 -> bf16 (RNE)
__device__ __forceinline__ ushort f2bf(float f) {
    union { float f; uint32_t u; } v; v.f = f;
    uint32_t lsb = (v.u >> 16) & 1u;
    return (ushort)((v.u + 0x7fffu + lsb) >> 16);
}

// two fp32 -> packed bf16x2 (round-half-up; P-matrix only)
__device__ __forceinline__ uint32_t packbf(float a, float b) {
    union { float f; uint32_t u; } x, y; x.f = a; y.f = b;
    return ((x.u + 0x8000u) >> 16) | ((y.u + 0x8000u) & 0xffff0000u);
}

__device__ __forceinline__ bf16x8 ldfrag(const ushort* p) {
    union { uint4 u; bf16x8 b; } cv;
    cv.u = *(const uint4*)p;
    return cv.b;
}

// ---------------- convert kernels ----------------

__global__ void cvt_x_kernel(const float* __restrict__ x, ushort* __restrict__ xb) {
    int i = blockIdx.x * 256 + threadIdx.x;
    float4 v = ((const float4*)x)[i];
    ushort4 o;
    o.x = f2bf(v.x); o.y = f2bf(v.y); o.z = f2bf(v.z); o.w = f2bf(v.w);
    ((ushort4*)xb)[i] = o;
}

__global__ void transpose_cvt4_kernel(
    const float* __restrict__ W0, const float* __restrict__ W1,
    const float* __restrict__ W2, const float* __restrict__ W3,
    ushort* __restrict__ D0, ushort* __restrict__ D1,
    ushort* __restrict__ D2, ushort* __restrict__ D3) {
    const float* W; ushort* D;
    switch (blockIdx.z) {
        case 0: W = W0; D = D0; break;
        case 1: W = W1; D = D1; break;
        case 2: W = W2; D = D2; break;
        default: W = W3; D = D3; break;
    }
    __shared__ float tile[32][33];
    int bx = blockIdx.x * 32, by = blockIdx.y * 32;
    int tx = threadIdx.x, ty = threadIdx.y;
#pragma unroll
    for (int j = 0; j < 32; j += 8)
        tile[ty + j][tx] = W[(size_t)(by + ty + j) * D_MODEL + bx + tx];
    __syncthreads();
#pragma unroll
    for (int j = 0; j < 32; j += 8)
        D[(size_t)(bx + ty + j) * D_MODEL + by + tx] = f2bf(tile[tx][ty + j]);
}

__global__ void cvt_bias_kernel(const float* __restrict__ bq, const float* __restrict__ bk,
                                const float* __restrict__ bv, float* __restrict__ out) {
    int i = blockIdx.x * 256 + threadIdx.x;  // 3072
    float v = (i < 1024) ? bq[i] : (i < 2048 ? bk[i - 1024] : bv[i - 2048]);
    out[i] = v;
}

// ---------------- MFMA GEMM: triple-buffer, depth-2 DMA prefetch, raw barriers --
// MODE 0: tile 128x128, grid 768, N-striped XCD; QKV scatter epilogue
//         (Q pre-scaled by 1/8 * log2e for the exp2 softmax).
// MODE 1: tile 128x64, grid 512, M-striped XCD (A 1MB + B 2MB L2-resident);
//         out = acc + bias + x residual (fp32).
template <int MODE>
__global__ __launch_bounds__(256) void gemm_kernel(
    const ushort* __restrict__ A, const ushort* __restrict__ Bt,
    const float* __restrict__ bias,
    ushort* __restrict__ outQ, ushort* __restrict__ outK, ushort* __restrict__ outVt,
    const float* __restrict__ xres, float* __restrict__ outF) {
    constexpr int BN = (MODE == 0) ? 128 : 64;
    constexpr int NI = (MODE == 0) ? 4 : 2;
    constexpr int NS = (MODE == 0) ? 4 : 3;   // DMA instrs per wave per stage
    __shared__ __align__(16) ushort sA[3][128 * 32];
    __shared__ __align__(16) ushort sB[3][BN * 32];
    const int tid = threadIdx.x;
    const int wave = tid >> 6, lane = tid & 63;
    const int lr = lane & 15, lq = lane >> 4;
    const int srow = lane >> 2;                        // 16 rows per DMA instr
    const int sc = (lane & 3) ^ ((lane >> 4) & 3);     // swizzled logical chunk

    const int bid = blockIdx.x;
    const int xcd = bid & 7, lb = bid >> 3;
    int bx, by;
    if (MODE == 0) { bx = xcd * 3 + (lb % 3); by = lb / 3; }       // N-stripe
    else           { by = xcd * 4 + (lb & 3); bx = lb >> 2; }      // M-stripe
    const int blockM = by * 128;
    const int blockN = bx * BN;
    const int waveM = (wave >> 1) * 64;
    const int waveN = (MODE == 0) ? (wave & 1) * 64 : (wave & 1) * 32;

    auto stage = [&](int k0, ushort* a, ushort* b) {
#pragma unroll
        for (int t = 0; t < 2; t++) {
            int row = wave * 32 + t * 16 + srow;
            async16(&A[(size_t)(blockM + row) * D_MODEL + k0 + sc * 8],
                    &a[(wave * 32 + t * 16) * 32]);
        }
        if (MODE == 0) {
#pragma unroll
            for (int t = 0; t < 2; t++) {
                int row = wave * 32 + t * 16 + srow;
                async16(&Bt[(size_t)(blockN + row) * D_MODEL + k0 + sc * 8],
                        &b[(wave * 32 + t * 16) * 32]);
            }
        } else {
            int row = wave * 16 + srow;
            async16(&Bt[(size_t)(blockN + row) * D_MODEL + k0 + sc * 8],
                    &b[wave * 16 * 32]);
        }
    };

    f32x4 acc[4][NI] = {};
    const int swz = (lq ^ ((lr >> 2) & 3)) * 8;

    stage(0, sA[0], sB[0]);
    stage(32, sA[1], sB[1]);
    __syncthreads();           // full drain once at start

    int cur = 0;
#pragma unroll 4
    for (int k = 0; k < 32; k++) {
        int nx = cur + 2; if (nx >= 3) nx -= 3;
        if (k + 2 < 32) stage((k + 2) * 32, sA[nx], sB[nx]);
        const ushort* a = sA[cur];
        const ushort* b = sB[cur];
        bf16x8 af[4], bfr[NI];
#pragma unroll
        for (int mi = 0; mi < 4; mi++)
            af[mi] = ldfrag(&a[(waveM + mi * 16 + lr) * 32 + swz]);
#pragma unroll
        for (int ni = 0; ni < NI; ni++)
            bfr[ni] = ldfrag(&b[(waveN + ni * 16 + lr) * 32 + swz]);
#pragma unroll
        for (int mi = 0; mi < 4; mi++)
#pragma unroll
            for (int ni = 0; ni < NI; ni++)
                acc[mi][ni] = __builtin_amdgcn_mfma_f32_16x16x32_bf16(
                    af[mi], bfr[ni], acc[mi][ni], 0, 0, 0);
        // tile k+1 must be landed (all waves) before next iter reads it;
        // tile k+2's NS DMAs may stay in flight.
        if (k < 30) pipe_barrier<NS>();
        else if (k == 30) pipe_barrier<0>();
        cur = (cur == 2) ? 0 : cur + 1;
    }

#pragma unroll
    for (int mi = 0; mi < 4; mi++) {
#pragma unroll
        for (int ni = 0; ni < NI; ni++) {
#pragma unroll
            for (int r = 0; r < 4; r++) {
                int m = blockM + waveM + mi * 16 + lq * 4 + r;
                int n = blockN + waveN + ni * 16 + lr;
                float v = acc[mi][ni][r] + bias[n];
                if (MODE == 0) {
                    int which = n >> 10, c = n & 1023;
                    int h = c >> 6, d = c & 63;
                    int b2 = m >> 11, s = m & 2047;
                    size_t bh = (size_t)(b2 * NH + h);
                    if (which == 0)   // fold softmax scale and log2(e) for exp2
                        outQ[(bh * S_LEN + s) * DK + d] = f2bf(v * 0.1803368801f);
                    else if (which == 1)
                        outK[(bh * S_LEN + s) * DK + d] = f2bf(v);
                    else
                        outVt[(bh * DK + d) * S_LEN + s] = f2bf(v);
                } else {
                    size_t idx = (size_t)m * D_MODEL + n;
                    outF[idx] = v + xres[idx];
                }
            }
        }
    }
}

// ---------------- flash attention -------------------------------------------
// q-tile 64, grid 1024 (4 blocks/CU -> 16 waves/CU). Wave owns 16 q-rows.
// S^T = K.Q^T so P exits MFMA k-contiguous; P LDS region aliases the (consumed)
// per-wave Q region. Row-sums via MFMA against an all-ones B fragment (lands in
// cacc layout -> no shuffles). exp2 with scale*log2e folded into Q upstream.
__global__ __launch_bounds__(256, 4) void attn_kernel(
    const ushort* __restrict__ Q, const ushort* __restrict__ Km,
    const ushort* __restrict__ Vt, ushort* __restrict__ ctx) {
    const int bid = blockIdx.x;
    const int xcd = bid & 7, lb = bid >> 3;
    const int bh = xcd * 4 + (lb & 3);
    const int qt = lb >> 2;                 // 32 q-tiles of 64
    const int q0 = qt * 64;
    __shared__ __align__(16) ushort sQP[4][16 * 64];  // per-wave Q, then P (8 KB)
    __shared__ __align__(16) ushort sK[64 * 64];      // [kpos][d] swizzled (8 KB)
    __shared__ __align__(16) ushort sV[64 * 64];      // [d][kpos] swizzled (8 KB)
    const int tid = threadIdx.x;
    const int wave = tid >> 6, lane = tid & 63;
    const int lr = lane & 15, lq = lane >> 4;
    const int srow = lane >> 3, sp = lane & 7;        // 128B-row staging
    const ushort* Qh = Q + (size_t)bh * S_LEN * DK;
    const ushort* Kh = Km + (size_t)bh * S_LEN * DK;
    const ushort* Vh = Vt + (size_t)bh * DK * S_LEN;
    ushort* sPw = sQP[wave];

    // stage this wave's 16 Q rows into its own region
#pragma unroll
    for (int t = 0; t < 2; t++) {
        int row = t * 8 + srow;                       // local 0..15
        int c = sp ^ (row & 7);
        async16(&Qh[(size_t)(q0 + wave * 16 + row) * DK + c * 8],
                &sPw[t * 8 * 64]);
    }
    __syncthreads();

    // hoist Q fragments to registers (B-operand for S^T)
    bf16x8 qf[2];
#pragma unroll
    for (int kk = 0; kk < 2; kk++)
        qf[kk] = ldfrag(&sPw[lr * 64 + (((kk * 4 + lq) ^ (lr & 7)) * 8)]);

    // all-ones B fragment for MFMA row-sums
    union { uint4 u; bf16x8 b; } one_u;
    one_u.u = make_uint4(0x3F803F80u, 0x3F803F80u, 0x3F803F80u, 0x3F803F80u);
    const bf16x8 ones = one_u.b;

    f32x4 cacc[4] = {};
    f32x4 ssum = {};

    for (int k0 = 0; k0 < S_LEN; k0 += 64) {
        __syncthreads();                              // prev iter reads done
#pragma unroll
        for (int t = 0; t < 2; t++) {
            int row = wave * 16 + t * 8 + srow;
            int c = sp ^ (row & 7);
            async16(&Kh[(size_t)(k0 + row) * DK + c * 8], &sK[(wave * 16 + t * 8) * 64]);
            async16(&Vh[(size_t)row * S_LEN + k0 + c * 8], &sV[(wave * 16 + t * 8) * 64]);
        }
        __syncthreads();                              // drains DMA (vmcnt0 + barrier)

        // S^T = K . Q^T : 16 q-cols, 64 kpos-rows
        f32x4 sacc[4] = {};
#pragma unroll
        for (int kk = 0; kk < 2; kk++) {
            int swz = ((kk * 4 + lq) ^ (lr & 7)) * 8;
#pragma unroll
            for (int nj = 0; nj < 4; nj++) {
                bf16x8 kf = ldfrag(&sK[(nj * 16 + lr) * 64 + swz]);
                sacc[nj] = __builtin_amdgcn_mfma_f32_16x16x32_bf16(
                    kf, qf[kk], sacc[nj], 0, 0, 0);
            }
        }

        // P = exp2(S^T) -> packed bf16, swizzled store into own (Q) region
#pragma unroll
        for (int nj = 0; nj < 4; nj++) {
            float p0 = fast_exp2(sacc[nj][0]);
            float p1 = fast_exp2(sacc[nj][1]);
            float p2 = fast_exp2(sacc[nj][2]);
            float p3 = fast_exp2(sacc[nj][3]);
            uint2 w;
            w.x = packbf(p0, p1);
            w.y = packbf(p2, p3);
            int physc = (nj * 2 + (lq >> 1)) ^ (lr & 7);
            *(uint2*)&sPw[lr * 64 + physc * 8 + (lq & 1) * 4] = w;
        }

        // ctx += P.V ; row-sums += P.1 (same-wave LDS: in-order, no barrier)
#pragma unroll
        for (int ks = 0; ks < 2; ks++) {
            bf16x8 pf = ldfrag(&sPw[lr * 64 + (((ks * 4 + lq) ^ (lr & 7)) * 8)]);
            int swz = ((ks * 4 + lq) ^ (lr & 7)) * 8;
#pragma unroll
            for (int nd = 0; nd < 4; nd++) {
                bf16x8 vf = ldfrag(&sV[(nd * 16 + lr) * 64 + swz]);
                cacc[nd] = __builtin_amdgcn_mfma_f32_16x16x32_bf16(
                    pf, vf, cacc[nd], 0, 0, 0);
            }
            ssum = __builtin_amdgcn_mfma_f32_16x16x32_bf16(pf, ones, ssum, 0, 0, 0);
        }
    }

    // normalize and store: ssum layout == cacc layout (q = lq*4+r), no shuffles
    const int b = bh >> 4, h = bh & 15;
    float inv[4];
#pragma unroll
    for (int r = 0; r < 4; r++) inv[r] = __builtin_amdgcn_rcpf(ssum[r]);
#pragma unroll
    for (int nd = 0; nd < 4; nd++)
#pragma unroll
        for (int r = 0; r < 4; r++) {
            int qrow = q0 + wave * 16 + lq * 4 + r;
            int d = nd * 16 + lr;
            float v = cacc[nd][r] * inv[r];
            ctx[(size_t)(b * S_LEN + qrow) * D_MODEL + h * DK + d] = f2bf(v);
        }
}

// ---------------- launch ----------------

extern "C" void kernel_launch(void* const* d_in, const int* in_sizes, int n_in,
                              void* d_out, int out_size, void* d_ws, size_t ws_size,
                              hipStream_t stream) {
    const float* x  = (const float*)d_in[0];
    const float* Wq = (const float*)d_in[1];
    const float* bq = (const float*)d_in[2];
    const float* Wk = (const float*)d_in[3];
    const float* bk = (const float*)d_in[4];
    const float* Wv = (const float*)d_in[5];
    const float* bv = (const float*)d_in[6];
    const float* Wo = (const float*)d_in[7];
    const float* bo = (const float*)d_in[8];

    char* ws = (char*)d_ws;
    ushort* xb    = (ushort*)(ws);                        // 8 MB  [4096][1024] bf16
    ushort* wqkv  = (ushort*)(ws + (8ull  << 20));        // 6 MB  [3072][1024] bf16 (B^T)
    ushort* wo_t  = (ushort*)(ws + (14ull << 20));        // 2 MB  [1024][1024] bf16 (B^T)
    ushort* qbuf  = (ushort*)(ws + (16ull << 20));        // 8 MB  [32][2048][64]
    ushort* kbuf  = (ushort*)(ws + (24ull << 20));        // 8 MB  [32][2048][64]
    ushort* vtb   = (ushort*)(ws + (32ull << 20));        // 8 MB  [32][64][2048]
    ushort* ctx   = (ushort*)(ws + (40ull << 20));        // 8 MB  [4096][1024]
    float*  biasq = (float*)(ws + (48ull << 20));         // 12 KB [3072]

    cvt_x_kernel<<<4096, 256, 0, stream>>>(x, xb);
    transpose_cvt4_kernel<<<dim3(32, 32, 4), dim3(32, 8), 0, stream>>>(
        Wq, Wk, Wv, Wo, wqkv, wqkv + 1024 * 1024, wqkv + 2 * 1024 * 1024, wo_t);
    cvt_bias_kernel<<<12, 256, 0, stream>>>(bq, bk, bv, biasq);

    gemm_kernel<0><<<768, 256, 0, stream>>>(
        xb, wqkv, biasq, qbuf, kbuf, vtb, nullptr, nullptr);
    attn_kernel<<<1024, 256, 0, stream>>>(qbuf, kbuf, vtb, ctx);
    gemm_kernel<1><<<512, 256, 0, stream>>>(
        ctx, wo_t, bo, nullptr, nullptr, nullptr, x, (float*)d_out);
}

// Round 5
// 211.926 us; speedup vs baseline: 1.0267x; 1.0267x over previous
//
#include <hip/hip_runtime.h>
#include <hip/hip_bf16.h>
#include <stdint.h>

#define D_MODEL 1024
#define NH 16
#define DK 64
#define S_LEN 2048

typedef __attribute__((ext_vector_type(8))) __bf16 bf16x8;
typedef __attribute__((ext_vector_type(4))) float f32x4;

#define GLOBAL_AS __attribute__((address_space(1)))
#define LDS_AS    __attribute__((address_space(3)))

// async global->LDS DMA, 16B per lane; lane i's 16B lands at ldsbase + i*16.
__device__ __forceinline__ void async16(const ushort* g, ushort* l) {
    __builtin_amdgcn_global_load_lds(
        (const GLOBAL_AS uint32_t*)(uintptr_t)(const void*)g,
        (LDS_AS uint32_t*)(uint32_t)(uintptr_t)(void*)l,
        16, 0, 0);
}

// raw barrier with fine-grained vmcnt: waits until <=N VMEM ops outstanding
// (the depth-2 prefetch issued this iter stays in flight across the barrier).
template <int N>
__device__ __forceinline__ void pipe_barrier() {
    asm volatile("s_waitcnt vmcnt(%0)\n\ts_barrier" :: "n"(N) : "memory");
}

__device__ __forceinline__ float fast_exp2(float x) {
    float r;
    asm("v_exp_f32 %0, %1" : "=v"(r) : "v"(x));   // D = 2^S0
    return r;
}

// fp32 -> bf16 (RNE)
__device__ __forceinline__ ushort f2bf(float f) {
    union { float f; uint32_t u; } v; v.f = f;
    uint32_t lsb = (v.u >> 16) & 1u;
    return (ushort)((v.u + 0x7fffu + lsb) >> 16);
}

// two fp32 -> packed bf16x2 (round-half-up; P-matrix only)
__device__ __forceinline__ uint32_t packbf(float a, float b) {
    union { float f; uint32_t u; } x, y; x.f = a; y.f = b;
    return ((x.u + 0x8000u) >> 16) | ((y.u + 0x8000u) & 0xffff0000u);
}

__device__ __forceinline__ bf16x8 ldfrag(const ushort* p) {
    union { uint4 u; bf16x8 b; } cv;
    cv.u = *(const uint4*)p;
    return cv.b;
}

// ---------------- convert kernels ----------------

__global__ void cvt_x_kernel(const float* __restrict__ x, ushort* __restrict__ xb) {
    int i = blockIdx.x * 256 + threadIdx.x;
    float4 v = ((const float4*)x)[i];
    ushort4 o;
    o.x = f2bf(v.x); o.y = f2bf(v.y); o.z = f2bf(v.z); o.w = f2bf(v.w);
    ((ushort4*)xb)[i] = o;
}

__global__ void transpose_cvt4_kernel(
    const float* __restrict__ W0, const float* __restrict__ W1,
    const float* __restrict__ W2, const float* __restrict__ W3,
    ushort* __restrict__ D0, ushort* __restrict__ D1,
    ushort* __restrict__ D2, ushort* __restrict__ D3) {
    const float* W; ushort* D;
    switch (blockIdx.z) {
        case 0: W = W0; D = D0; break;
        case 1: W = W1; D = D1; break;
        case 2: W = W2; D = D2; break;
        default: W = W3; D = D3; break;
    }
    __shared__ float tile[32][33];
    int bx = blockIdx.x * 32, by = blockIdx.y * 32;
    int tx = threadIdx.x, ty = threadIdx.y;
#pragma unroll
    for (int j = 0; j < 32; j += 8)
        tile[ty + j][tx] = W[(size_t)(by + ty + j) * D_MODEL + bx + tx];
    __syncthreads();
#pragma unroll
    for (int j = 0; j < 32; j += 8)
        D[(size_t)(bx + ty + j) * D_MODEL + by + tx] = f2bf(tile[tx][ty + j]);
}

__global__ void cvt_bias_kernel(const float* __restrict__ bq, const float* __restrict__ bk,
                                const float* __restrict__ bv, float* __restrict__ out) {
    int i = blockIdx.x * 256 + threadIdx.x;  // 3072
    float v = (i < 1024) ? bq[i] : (i < 2048 ? bk[i - 1024] : bv[i - 2048]);
    out[i] = v;
}

// ---------------- MFMA GEMM: triple-buffer, depth-2 DMA prefetch, raw barriers --
// MODE 0: tile 128x128, grid 768, N-striped XCD; QKV scatter epilogue
//         (Q pre-scaled by 1/8 * log2e for the exp2 softmax).
// MODE 1: tile 128x64, grid 512, M-striped XCD; out = acc + bias + residual.
template <int MODE>
__global__ __launch_bounds__(256) void gemm_kernel(
    const ushort* __restrict__ A, const ushort* __restrict__ Bt,
    const float* __restrict__ bias,
    ushort* __restrict__ outQ, ushort* __restrict__ outK, ushort* __restrict__ outVt,
    const float* __restrict__ xres, float* __restrict__ outF) {
    constexpr int BN = (MODE == 0) ? 128 : 64;
    constexpr int NI = (MODE == 0) ? 4 : 2;
    constexpr int NS = (MODE == 0) ? 4 : 3;   // DMA instrs per wave per stage
    __shared__ __align__(16) ushort sA[3][128 * 32];
    __shared__ __align__(16) ushort sB[3][BN * 32];
    const int tid = threadIdx.x;
    const int wave = tid >> 6, lane = tid & 63;
    const int lr = lane & 15, lq = lane >> 4;
    const int srow = lane >> 2;                        // 16 rows per DMA instr
    const int sc = (lane & 3) ^ ((lane >> 4) & 3);     // swizzled logical chunk

    const int bid = blockIdx.x;
    const int xcd = bid & 7, lb = bid >> 3;
    int bx, by;
    if (MODE == 0) { bx = xcd * 3 + (lb % 3); by = lb / 3; }       // N-stripe
    else           { by = xcd * 4 + (lb & 3); bx = lb >> 2; }      // M-stripe
    const int blockM = by * 128;
    const int blockN = bx * BN;
    const int waveM = (wave >> 1) * 64;
    const int waveN = (MODE == 0) ? (wave & 1) * 64 : (wave & 1) * 32;

    auto stage = [&](int k0, ushort* a, ushort* b) {
#pragma unroll
        for (int t = 0; t < 2; t++) {
            int row = wave * 32 + t * 16 + srow;
            async16(&A[(size_t)(blockM + row) * D_MODEL + k0 + sc * 8],
                    &a[(wave * 32 + t * 16) * 32]);
        }
        if (MODE == 0) {
#pragma unroll
            for (int t = 0; t < 2; t++) {
                int row = wave * 32 + t * 16 + srow;
                async16(&Bt[(size_t)(blockN + row) * D_MODEL + k0 + sc * 8],
                        &b[(wave * 32 + t * 16) * 32]);
            }
        } else {
            int row = wave * 16 + srow;
            async16(&Bt[(size_t)(blockN + row) * D_MODEL + k0 + sc * 8],
                    &b[wave * 16 * 32]);
        }
    };

    f32x4 acc[4][NI] = {};
    const int swz = (lq ^ ((lr >> 2) & 3)) * 8;

    stage(0, sA[0], sB[0]);
    stage(32, sA[1], sB[1]);
    __syncthreads();           // full drain once at start

    int cur = 0;
#pragma unroll 4
    for (int k = 0; k < 32; k++) {
        int nx = cur + 2; if (nx >= 3) nx -= 3;
        if (k + 2 < 32) stage((k + 2) * 32, sA[nx], sB[nx]);
        const ushort* a = sA[cur];
        const ushort* b = sB[cur];
        bf16x8 af[4], bfr[NI];
#pragma unroll
        for (int mi = 0; mi < 4; mi++)
            af[mi] = ldfrag(&a[(waveM + mi * 16 + lr) * 32 + swz]);
#pragma unroll
        for (int ni = 0; ni < NI; ni++)
            bfr[ni] = ldfrag(&b[(waveN + ni * 16 + lr) * 32 + swz]);
#pragma unroll
        for (int mi = 0; mi < 4; mi++)
#pragma unroll
            for (int ni = 0; ni < NI; ni++)
                acc[mi][ni] = __builtin_amdgcn_mfma_f32_16x16x32_bf16(
                    af[mi], bfr[ni], acc[mi][ni], 0, 0, 0);
        if (k < 30) pipe_barrier<NS>();
        else if (k == 30) pipe_barrier<0>();
        cur = (cur == 2) ? 0 : cur + 1;
    }

#pragma unroll
    for (int mi = 0; mi < 4; mi++) {
#pragma unroll
        for (int ni = 0; ni < NI; ni++) {
#pragma unroll
            for (int r = 0; r < 4; r++) {
                int m = blockM + waveM + mi * 16 + lq * 4 + r;
                int n = blockN + waveN + ni * 16 + lr;
                float v = acc[mi][ni][r] + bias[n];
                if (MODE == 0) {
                    int which = n >> 10, c = n & 1023;
                    int h = c >> 6, d = c & 63;
                    int b2 = m >> 11, s = m & 2047;
                    size_t bh = (size_t)(b2 * NH + h);
                    if (which == 0)   // fold softmax scale and log2(e) for exp2
                        outQ[(bh * S_LEN + s) * DK + d] = f2bf(v * 0.1803368801f);
                    else if (which == 1)
                        outK[(bh * S_LEN + s) * DK + d] = f2bf(v);
                    else
                        outVt[(bh * DK + d) * S_LEN + s] = f2bf(v);
                } else {
                    size_t idx = (size_t)m * D_MODEL + n;
                    outF[idx] = v + xres[idx];
                }
            }
        }
    }
}

// ---------------- flash attention -------------------------------------------
// q-tile 128 (32/wave), grid 512. Triple-buffered K/V, depth-2 DMA prefetch,
// fine-grained vmcnt barriers. Per wave-iter: 24 KB LDS feeds 524K FLOP
// (22 FLOP/B vs 13 at q=16). S^T = K.Q^T so P exits MFMA k-contiguous;
// P aliases the consumed per-wave Q region. Row-sums via MFMA vs all-ones.
__global__ __launch_bounds__(256, 2) void attn_kernel(
    const ushort* __restrict__ Q, const ushort* __restrict__ Km,
    const ushort* __restrict__ Vt, ushort* __restrict__ ctx) {
    const int bid = blockIdx.x;
    const int xcd = bid & 7, lb = bid >> 3;
    const int bh = xcd * 4 + (lb & 3);
    const int qt = lb >> 2;                 // 16 q-tiles of 128
    const int q0 = qt * 128;
    __shared__ __align__(16) ushort sK[3][64 * 64];   // [kpos][d] swizzled, 24 KB
    __shared__ __align__(16) ushort sV[3][64 * 64];   // [d][kpos] swizzled, 24 KB
    __shared__ __align__(16) ushort sQP[4][32 * 64];  // per-wave Q then P, 16 KB
    const int tid = threadIdx.x;
    const int wave = tid >> 6, lane = tid & 63;
    const int lr = lane & 15, lq = lane >> 4;
    const int srow = lane >> 3, sp = lane & 7;        // 128B-row staging
    const ushort* Qh = Q + (size_t)bh * S_LEN * DK;
    const ushort* Kh = Km + (size_t)bh * S_LEN * DK;
    const ushort* Vh = Vt + (size_t)bh * DK * S_LEN;
    ushort* sPw = sQP[wave];

    // stage this wave's 32 Q rows into its own (future-P) region
#pragma unroll
    for (int t = 0; t < 4; t++) {
        int row = t * 8 + srow;                       // local 0..31
        int c = sp ^ (row & 7);
        async16(&Qh[(size_t)(q0 + wave * 32 + row) * DK + c * 8],
                &sPw[t * 8 * 64]);
    }

    auto stageKV = [&](int k0, int buf) {
#pragma unroll
        for (int t = 0; t < 2; t++) {
            int row = wave * 16 + t * 8 + srow;
            int c = sp ^ (row & 7);
            async16(&Kh[(size_t)(k0 + row) * DK + c * 8],
                    &sK[buf][(wave * 16 + t * 8) * 64]);
            async16(&Vh[(size_t)row * S_LEN + k0 + c * 8],
                    &sV[buf][(wave * 16 + t * 8) * 64]);
        }
    };

    stageKV(0, 0);
    stageKV(64, 1);
    __syncthreads();   // drains Q + bufs 0,1

    // hoist Q fragments to registers (B-operand for S^T): q = wave*32+nj*16+lr
    bf16x8 qf[2][2];
#pragma unroll
    for (int nj = 0; nj < 2; nj++)
#pragma unroll
        for (int kk = 0; kk < 2; kk++)
            qf[nj][kk] = ldfrag(&sPw[(nj * 16 + lr) * 64 +
                                     (((kk * 4 + lq) ^ (lr & 7)) * 8)]);

    union { uint4 u; bf16x8 b; } one_u;
    one_u.u = make_uint4(0x3F803F80u, 0x3F803F80u, 0x3F803F80u, 0x3F803F80u);
    const bf16x8 ones = one_u.b;

    f32x4 cacc[2][4] = {};
    f32x4 ssum[2] = {};

    int cur = 0;
    for (int k = 0; k < 32; k++) {
        int nx = cur + 2; if (nx >= 3) nx -= 3;
        if (k + 2 < 32) stageKV((k + 2) * 64, nx);
        const ushort* sk = sK[cur];
        const ushort* sv = sV[cur];

        // S^T = K . Q^T : 64 kpos rows (4 mi), 32 q cols (2 nj)
        f32x4 sacc[4][2] = {};
#pragma unroll
        for (int kk = 0; kk < 2; kk++) {
            bf16x8 kf[4];
            int swz = ((kk * 4 + lq) ^ (lr & 7)) * 8;
#pragma unroll
            for (int mi = 0; mi < 4; mi++)
                kf[mi] = ldfrag(&sk[(mi * 16 + lr) * 64 + swz]);
#pragma unroll
            for (int mi = 0; mi < 4; mi++)
#pragma unroll
                for (int nj = 0; nj < 2; nj++)
                    sacc[mi][nj] = __builtin_amdgcn_mfma_f32_16x16x32_bf16(
                        kf[mi], qf[nj][kk], sacc[mi][nj], 0, 0, 0);
        }

        // P = exp2(S^T) -> packed bf16 to per-wave region.
        // lane holds q = nj*16+lr, kpos = mi*16 + lq*4 + r (contiguous in r).
#pragma unroll
        for (int mi = 0; mi < 4; mi++)
#pragma unroll
            for (int nj = 0; nj < 2; nj++) {
                float p0 = fast_exp2(sacc[mi][nj][0]);
                float p1 = fast_exp2(sacc[mi][nj][1]);
                float p2 = fast_exp2(sacc[mi][nj][2]);
                float p3 = fast_exp2(sacc[mi][nj][3]);
                uint2 w;
                w.x = packbf(p0, p1);
                w.y = packbf(p2, p3);
                int physc = (mi * 2 + (lq >> 1)) ^ (lr & 7);
                *(uint2*)&sPw[(nj * 16 + lr) * 64 + physc * 8 + (lq & 1) * 4] = w;
            }

        // ctx += P.V ; rowsum += P.1 (same-wave LDS, no barrier)
#pragma unroll
        for (int ks = 0; ks < 2; ks++) {
            bf16x8 pf[2], vf[4];
            int swz = ((ks * 4 + lq) ^ (lr & 7)) * 8;
#pragma unroll
            for (int nj = 0; nj < 2; nj++)
                pf[nj] = ldfrag(&sPw[(nj * 16 + lr) * 64 + swz]);
#pragma unroll
            for (int nd = 0; nd < 4; nd++)
                vf[nd] = ldfrag(&sv[(nd * 16 + lr) * 64 + swz]);
#pragma unroll
            for (int nj = 0; nj < 2; nj++)
#pragma unroll
                for (int nd = 0; nd < 4; nd++)
                    cacc[nj][nd] = __builtin_amdgcn_mfma_f32_16x16x32_bf16(
                        pf[nj], vf[nd], cacc[nj][nd], 0, 0, 0);
#pragma unroll
            for (int nj = 0; nj < 2; nj++)
                ssum[nj] = __builtin_amdgcn_mfma_f32_16x16x32_bf16(
                    pf[nj], ones, ssum[nj], 0, 0, 0);
        }

        if (k < 30) pipe_barrier<4>();
        else if (k == 30) pipe_barrier<0>();
        cur = (cur == 2) ? 0 : cur + 1;
    }

    // normalize + store; ssum layout == cacc layout (q = nj*16 + lq*4 + r)
    const int b = bh >> 4, h = bh & 15;
    float inv[2][4];
#pragma unroll
    for (int nj = 0; nj < 2; nj++)
#pragma unroll
        for (int r = 0; r < 4; r++)
            inv[nj][r] = __builtin_amdgcn_rcpf(ssum[nj][r]);
#pragma unroll
    for (int nj = 0; nj < 2; nj++)
#pragma unroll
        for (int nd = 0; nd < 4; nd++)
#pragma unroll
            for (int r = 0; r < 4; r++) {
                int qrow = q0 + wave * 32 + nj * 16 + lq * 4 + r;
                int d = nd * 16 + lr;
                float v = cacc[nj][nd][r] * inv[nj][r];
                ctx[(size_t)(b * S_LEN + qrow) * D_MODEL + h * DK + d] = f2bf(v);
            }
}

// ---------------- launch ----------------

extern "C" void kernel_launch(void* const* d_in, const int* in_sizes, int n_in,
                              void* d_out, int out_size, void* d_ws, size_t ws_size,
                              hipStream_t stream) {
    const float* x  = (const float*)d_in[0];
    const float* Wq = (const float*)d_in[1];
    const float* bq = (const float*)d_in[2];
    const float* Wk = (const float*)d_in[3];
    const float* bk = (const float*)d_in[4];
    const float* Wv = (const float*)d_in[5];
    const float* bv = (const float*)d_in[6];
    const float* Wo = (const float*)d_in[7];
    const float* bo = (const float*)d_in[8];

    char* ws = (char*)d_ws;
    ushort* xb    = (ushort*)(ws);                        // 8 MB  [4096][1024] bf16
    ushort* wqkv  = (ushort*)(ws + (8ull  << 20));        // 6 MB  [3072][1024] bf16 (B^T)
    ushort* wo_t  = (ushort*)(ws + (14ull << 20));        // 2 MB  [1024][1024] bf16 (B^T)
    ushort* qbuf  = (ushort*)(ws + (16ull << 20));        // 8 MB  [32][2048][64]
    ushort* kbuf  = (ushort*)(ws + (24ull << 20));        // 8 MB  [32][2048][64]
    ushort* vtb   = (ushort*)(ws + (32ull << 20));        // 8 MB  [32][64][2048]
    ushort* ctx   = (ushort*)(ws + (40ull << 20));        // 8 MB  [4096][1024]
    float*  biasq = (float*)(ws + (48ull << 20));         // 12 KB [3072]

    cvt_x_kernel<<<4096, 256, 0, stream>>>(x, xb);
    transpose_cvt4_kernel<<<dim3(32, 32, 4), dim3(32, 8), 0, stream>>>(
        Wq, Wk, Wv, Wo, wqkv, wqkv + 1024 * 1024, wqkv + 2 * 1024 * 1024, wo_t);
    cvt_bias_kernel<<<12, 256, 0, stream>>>(bq, bk, bv, biasq);

    gemm_kernel<0><<<768, 256, 0, stream>>>(
        xb, wqkv, biasq, qbuf, kbuf, vtb, nullptr, nullptr);
    attn_kernel<<<512, 256, 0, stream>>>(qbuf, kbuf, vtb, ctx);
    gemm_kernel<1><<<512, 256, 0, stream>>>(
        ctx, wo_t, bo, nullptr, nullptr, nullptr, x, (float*)d_out);
}

// Round 6
// 206.926 us; speedup vs baseline: 1.0516x; 1.0242x over previous
//
#include <hip/hip_runtime.h>
#include <hip/hip_bf16.h>
#include <stdint.h>

#define D_MODEL 1024
#define NH 16
#define DK 64
#define S_LEN 2048

typedef __attribute__((ext_vector_type(8))) __bf16 bf16x8;
typedef __attribute__((ext_vector_type(4))) float f32x4;

#define GLOBAL_AS __attribute__((address_space(1)))
#define LDS_AS    __attribute__((address_space(3)))

// async global->LDS DMA, 16B per lane; lane i's 16B lands at ldsbase + i*16.
__device__ __forceinline__ void async16(const ushort* g, ushort* l) {
    __builtin_amdgcn_global_load_lds(
        (const GLOBAL_AS uint32_t*)(uintptr_t)(const void*)g,
        (LDS_AS uint32_t*)(uint32_t)(uintptr_t)(void*)l,
        16, 0, 0);
}

// raw barrier with fine-grained vmcnt: waits until <=N VMEM ops outstanding.
template <int N>
__device__ __forceinline__ void pipe_barrier() {
    asm volatile("s_waitcnt vmcnt(%0)\n\ts_barrier" :: "n"(N) : "memory");
}

__device__ __forceinline__ float fast_exp2(float x) {
    float r;
    asm("v_exp_f32 %0, %1" : "=v"(r) : "v"(x));   // D = 2^S0
    return r;
}

// fp32 -> bf16 (RNE)
__device__ __forceinline__ ushort f2bf(float f) {
    union { float f; uint32_t u; } v; v.f = f;
    uint32_t lsb = (v.u >> 16) & 1u;
    return (ushort)((v.u + 0x7fffu + lsb) >> 16);
}

// two fp32 -> packed bf16x2 (round-half-up)
__device__ __forceinline__ uint32_t packbf(float a, float b) {
    union { float f; uint32_t u; } x, y; x.f = a; y.f = b;
    return ((x.u + 0x8000u) >> 16) | ((y.u + 0x8000u) & 0xffff0000u);
}

__device__ __forceinline__ bf16x8 ldfrag(const ushort* p) {
    union { uint4 u; bf16x8 b; } cv;
    cv.u = *(const uint4*)p;
    return cv.b;
}

// ---------------- convert kernels ----------------

__global__ void cvt_x_kernel(const float* __restrict__ x, ushort* __restrict__ xb) {
    int i = blockIdx.x * 256 + threadIdx.x;
    float4 v = ((const float4*)x)[i];
    ushort4 o;
    o.x = f2bf(v.x); o.y = f2bf(v.y); o.z = f2bf(v.z); o.w = f2bf(v.w);
    ((ushort4*)xb)[i] = o;
}

__global__ void transpose_cvt4_kernel(
    const float* __restrict__ W0, const float* __restrict__ W1,
    const float* __restrict__ W2, const float* __restrict__ W3,
    ushort* __restrict__ D0, ushort* __restrict__ D1,
    ushort* __restrict__ D2, ushort* __restrict__ D3) {
    const float* W; ushort* D;
    switch (blockIdx.z) {
        case 0: W = W0; D = D0; break;
        case 1: W = W1; D = D1; break;
        case 2: W = W2; D = D2; break;
        default: W = W3; D = D3; break;
    }
    __shared__ float tile[32][33];
    int bx = blockIdx.x * 32, by = blockIdx.y * 32;
    int tx = threadIdx.x, ty = threadIdx.y;
#pragma unroll
    for (int j = 0; j < 32; j += 8)
        tile[ty + j][tx] = W[(size_t)(by + ty + j) * D_MODEL + bx + tx];
    __syncthreads();
#pragma unroll
    for (int j = 0; j < 32; j += 8)
        D[(size_t)(bx + ty + j) * D_MODEL + by + tx] = f2bf(tile[tx][ty + j]);
}

__global__ void cvt_bias_kernel(const float* __restrict__ bq, const float* __restrict__ bk,
                                const float* __restrict__ bv, float* __restrict__ out) {
    int i = blockIdx.x * 256 + threadIdx.x;  // 3072
    float v = (i < 1024) ? bq[i] : (i < 2048 ? bk[i - 1024] : bv[i - 2048]);
    out[i] = v;
}

// ---------------- MFMA GEMM ---------------------------------------------------
// BK=32, FOUR buffers, depth-3 DMA prefetch, vmcnt pipe barriers.
// LDS tile layout: 128B rows holding 2 A-rows (64B each = 4 chunks of 16B);
// logical chunk L at phys L^(R&7) -> DMA-compatible and conflict-free reads.
// Epilogue goes through LDS so all global stores are coalesced dwordx4.
// MODE 0: tile 128x128, grid 768, N-striped XCD. Each block is wholly Q, K or V.
// MODE 1: tile 128x64, grid 512, M-striped XCD; out = acc + bias + residual.
template <int MODE>
__global__ __launch_bounds__(256) void gemm_kernel(
    const ushort* __restrict__ A, const ushort* __restrict__ Bt,
    const float* __restrict__ bias,
    ushort* __restrict__ outQ, ushort* __restrict__ outK, ushort* __restrict__ outVt,
    const float* __restrict__ xres, float* __restrict__ outF) {
    constexpr int BN = (MODE == 0) ? 128 : 64;
    constexpr int NI = (MODE == 0) ? 4 : 2;
    constexpr int NS = (MODE == 0) ? 4 : 3;        // per-wave DMA instrs / stage
    constexpr int ABUF = 4096;                     // ushorts per A buffer
    constexpr int BBUF = (MODE == 0) ? 4096 : 2048;
    constexpr int SMEM = (MODE == 0) ? 32768 : 24576;  // 64 / 48 KB
    __shared__ __align__(16) ushort smem[SMEM];
    ushort* sAb = smem;
    ushort* sBb = smem + 4 * ABUF;

    const int tid = threadIdx.x;
    const int wave = tid >> 6, lane = tid & 63;
    const int lr = lane & 15, lq = lane >> 4;
    const int srow = lane >> 3, sp = lane & 7;     // staging: 8 lanes / 128B row

    const int bid = blockIdx.x;
    const int xcd = bid & 7, lb = bid >> 3;
    int bx, by;
    if (MODE == 0) { bx = xcd * 3 + (lb % 3); by = lb / 3; }       // N-stripe
    else           { by = xcd * 4 + (lb & 3); bx = lb >> 2; }      // M-stripe
    const int blockM = by * 128;
    const int blockN = bx * BN;
    const int waveM = (wave >> 1) * 64;
    const int waveN = (MODE == 0) ? (wave & 1) * 64 : (wave & 1) * 32;

    // stage one BK=32 tile pair into buffer `buf`
    auto stage = [&](int k0, int buf) {
        ushort* a = sAb + buf * ABUF;
#pragma unroll
        for (int t = 0; t < 2; t++) {
            int Rb = wave * 16 + t * 8;            // uniform LDS row base
            int R = Rb + srow;
            int L = sp ^ (R & 7);
            int m = 2 * R + (L >> 2);
            int kc = L & 3;
            async16(&A[(size_t)(blockM + m) * D_MODEL + k0 + kc * 8], a + Rb * 64);
        }
        ushort* b = sBb + buf * BBUF;
        if (MODE == 0) {
#pragma unroll
            for (int t = 0; t < 2; t++) {
                int Rb = wave * 16 + t * 8;
                int R = Rb + srow;
                int L = sp ^ (R & 7);
                int n = 2 * R + (L >> 2);
                int kc = L & 3;
                async16(&Bt[(size_t)(blockN + n) * D_MODEL + k0 + kc * 8], b + Rb * 64);
            }
        } else {
            int Rb = wave * 8;
            int R = Rb + srow;
            int L = sp ^ (R & 7);
            int n = 2 * R + (L >> 2);
            int kc = L & 3;
            async16(&Bt[(size_t)(blockN + n) * D_MODEL + k0 + kc * 8], b + Rb * 64);
        }
    };

    // fragment read offsets (row-xor invariant across mi since rows step by 8)
    const int RA = (waveM >> 1) + (lr >> 1);
    const int offA = RA * 64 + ((((lr & 1) * 4 + lq) ^ (RA & 7)) * 8);
    const int RB = (waveN >> 1) + (lr >> 1);
    const int offB = RB * 64 + ((((lr & 1) * 4 + lq) ^ (RB & 7)) * 8);

    f32x4 acc[4][NI] = {};

    stage(0, 0);
    stage(32, 1);
    stage(64, 2);
    pipe_barrier<2 * NS>();   // buf0 landed; bufs 1,2 in flight

#pragma unroll 4
    for (int k = 0; k < 32; k++) {
        const int buf = k & 3;
        if (k + 3 < 32) stage((k + 3) * 32, (k + 3) & 3);
        const ushort* a = sAb + buf * ABUF;
        const ushort* b = sBb + buf * BBUF;
        bf16x8 af[4], bfr[NI];
#pragma unroll
        for (int mi = 0; mi < 4; mi++)
            af[mi] = ldfrag(&a[offA + mi * 512]);
#pragma unroll
        for (int ni = 0; ni < NI; ni++)
            bfr[ni] = ldfrag(&b[offB + ni * 512]);
#pragma unroll
        for (int mi = 0; mi < 4; mi++)
#pragma unroll
            for (int ni = 0; ni < NI; ni++)
                acc[mi][ni] = __builtin_amdgcn_mfma_f32_16x16x32_bf16(
                    af[mi], bfr[ni], acc[mi][ni], 0, 0, 0);
        if (k < 30) pipe_barrier<2 * NS>();       // awaited stage is 3 iters old
        else if (k == 30) pipe_barrier<0>();
    }
    __syncthreads();   // all K-loop LDS reads done; smem now reused for epilogue

    const int bglob = blockM >> 11;
    const int sbase = blockM & 2047;

    if (MODE == 0) {
        const int which = bx >> 3;                // 0=Q 1=K 2=V, uniform per block
        if (which < 2) {
            // C -> LDS [m][n], stride 136, then coalesced [bh][s][d] stores
            const float scale = (which == 0) ? 0.1803368801f : 1.0f;  // 1/8*log2e
#pragma unroll
            for (int ni = 0; ni < 4; ni++) {
                const int n_loc = waveN + ni * 16 + lr;
                const float bn = bias[blockN + n_loc];
#pragma unroll
                for (int mi = 0; mi < 4; mi++)
#pragma unroll
                    for (int r = 0; r < 4; r++) {
                        int m_loc = waveM + mi * 16 + lq * 4 + r;
                        smem[m_loc * 136 + n_loc] =
                            f2bf((acc[mi][ni][r] + bn) * scale);
                    }
            }
            __syncthreads();
            ushort* outp = (which == 0) ? outQ : outK;
            const int hbase = (which == 0) ? bx * 2 : (bx - 8) * 2;
#pragma unroll
            for (int j = 0; j < 8; j++) {
                int c = tid + j * 256;            // 2048 chunks of 16B
                int m = c >> 4, nc = c & 15;
                int hh = nc >> 3, d8 = nc & 7;
                uint4 w = *(uint4*)&smem[m * 136 + nc * 8];
                size_t bh = (size_t)(bglob * NH + hbase + hh);
                *(uint4*)&outp[(bh * S_LEN + sbase + m) * DK + d8 * 8] = w;
            }
        } else {
            // V: C -> LDS [n][m] (b64 packed writes), then [bh][d][s] stores
#pragma unroll
            for (int ni = 0; ni < 4; ni++) {
                const int n_loc = waveN + ni * 16 + lr;
                const float bn = bias[blockN + n_loc];
#pragma unroll
                for (int mi = 0; mi < 4; mi++) {
                    uint2 w;
                    w.x = packbf(acc[mi][ni][0] + bn, acc[mi][ni][1] + bn);
                    w.y = packbf(acc[mi][ni][2] + bn, acc[mi][ni][3] + bn);
                    int m_base = waveM + mi * 16 + lq * 4;
                    *(uint2*)&smem[n_loc * 136 + m_base] = w;
                }
            }
            __syncthreads();
            const int hbase = (bx - 16) * 2;
#pragma unroll
            for (int j = 0; j < 8; j++) {
                int c = tid + j * 256;
                int n_loc = c >> 4, m8 = c & 15;
                int d = n_loc & 63, hh = n_loc >> 6;
                uint4 w = *(uint4*)&smem[n_loc * 136 + m8 * 8];
                size_t bh = (size_t)(bglob * NH + hbase + hh);
                *(uint4*)&outVt[(bh * DK + d) * S_LEN + sbase + m8 * 8] = w;
            }
        }
    } else {
        // fp32 out: C+bias -> LDS [m][n] stride 68, then +residual float4 stores
        float* sCf = (float*)smem;
#pragma unroll
        for (int ni = 0; ni < 2; ni++) {
            const int n_loc = waveN + ni * 16 + lr;
            const float bn = bias[blockN + n_loc];
#pragma unroll
            for (int mi = 0; mi < 4; mi++)
#pragma unroll
                for (int r = 0; r < 4; r++) {
                    int m_loc = waveM + mi * 16 + lq * 4 + r;
                    sCf[m_loc * 68 + n_loc] = acc[mi][ni][r] + bn;
                }
        }
        __syncthreads();
#pragma unroll
        for (int j = 0; j < 8; j++) {
            int c = tid + j * 256;               // 2048 chunks of 16B
            int m = c >> 4, nc = c & 15;
            float4 v = *(float4*)&sCf[m * 68 + nc * 4];
            size_t idx = (size_t)(blockM + m) * D_MODEL + blockN + nc * 4;
            float4 xr = *(const float4*)&xres[idx];
            v.x += xr.x; v.y += xr.y; v.z += xr.z; v.w += xr.w;
            *(float4*)&outF[idx] = v;
        }
    }
}

// ---------------- flash attention (unchanged from R5) -------------------------
__global__ __launch_bounds__(256, 2) void attn_kernel(
    const ushort* __restrict__ Q, const ushort* __restrict__ Km,
    const ushort* __restrict__ Vt, ushort* __restrict__ ctx) {
    const int bid = blockIdx.x;
    const int xcd = bid & 7, lb = bid >> 3;
    const int bh = xcd * 4 + (lb & 3);
    const int qt = lb >> 2;
    const int q0 = qt * 128;
    __shared__ __align__(16) ushort sK[3][64 * 64];
    __shared__ __align__(16) ushort sV[3][64 * 64];
    __shared__ __align__(16) ushort sQP[4][32 * 64];
    const int tid = threadIdx.x;
    const int wave = tid >> 6, lane = tid & 63;
    const int lr = lane & 15, lq = lane >> 4;
    const int srow = lane >> 3, sp = lane & 7;
    const ushort* Qh = Q + (size_t)bh * S_LEN * DK;
    const ushort* Kh = Km + (size_t)bh * S_LEN * DK;
    const ushort* Vh = Vt + (size_t)bh * DK * S_LEN;
    ushort* sPw = sQP[wave];

#pragma unroll
    for (int t = 0; t < 4; t++) {
        int row = t * 8 + srow;
        int c = sp ^ (row & 7);
        async16(&Qh[(size_t)(q0 + wave * 32 + row) * DK + c * 8],
                &sPw[t * 8 * 64]);
    }

    auto stageKV = [&](int k0, int buf) {
#pragma unroll
        for (int t = 0; t < 2; t++) {
            int row = wave * 16 + t * 8 + srow;
            int c = sp ^ (row & 7);
            async16(&Kh[(size_t)(k0 + row) * DK + c * 8],
                    &sK[buf][(wave * 16 + t * 8) * 64]);
            async16(&Vh[(size_t)row * S_LEN + k0 + c * 8],
                    &sV[buf][(wave * 16 + t * 8) * 64]);
        }
    };

    stageKV(0, 0);
    stageKV(64, 1);
    __syncthreads();

    bf16x8 qf[2][2];
#pragma unroll
    for (int nj = 0; nj < 2; nj++)
#pragma unroll
        for (int kk = 0; kk < 2; kk++)
            qf[nj][kk] = ldfrag(&sPw[(nj * 16 + lr) * 64 +
                                     (((kk * 4 + lq) ^ (lr & 7)) * 8)]);

    union { uint4 u; bf16x8 b; } one_u;
    one_u.u = make_uint4(0x3F803F80u, 0x3F803F80u, 0x3F803F80u, 0x3F803F80u);
    const bf16x8 ones = one_u.b;

    f32x4 cacc[2][4] = {};
    f32x4 ssum[2] = {};

    int cur = 0;
    for (int k = 0; k < 32; k++) {
        int nx = cur + 2; if (nx >= 3) nx -= 3;
        if (k + 2 < 32) stageKV((k + 2) * 64, nx);
        const ushort* sk = sK[cur];
        const ushort* sv = sV[cur];

        f32x4 sacc[4][2] = {};
#pragma unroll
        for (int kk = 0; kk < 2; kk++) {
            bf16x8 kf[4];
            int swz = ((kk * 4 + lq) ^ (lr & 7)) * 8;
#pragma unroll
            for (int mi = 0; mi < 4; mi++)
                kf[mi] = ldfrag(&sk[(mi * 16 + lr) * 64 + swz]);
#pragma unroll
            for (int mi = 0; mi < 4; mi++)
#pragma unroll
                for (int nj = 0; nj < 2; nj++)
                    sacc[mi][nj] = __builtin_amdgcn_mfma_f32_16x16x32_bf16(
                        kf[mi], qf[nj][kk], sacc[mi][nj], 0, 0, 0);
        }

#pragma unroll
        for (int mi = 0; mi < 4; mi++)
#pragma unroll
            for (int nj = 0; nj < 2; nj++) {
                float p0 = fast_exp2(sacc[mi][nj][0]);
                float p1 = fast_exp2(sacc[mi][nj][1]);
                float p2 = fast_exp2(sacc[mi][nj][2]);
                float p3 = fast_exp2(sacc[mi][nj][3]);
                uint2 w;
                w.x = packbf(p0, p1);
                w.y = packbf(p2, p3);
                int physc = (mi * 2 + (lq >> 1)) ^ (lr & 7);
                *(uint2*)&sPw[(nj * 16 + lr) * 64 + physc * 8 + (lq & 1) * 4] = w;
            }

#pragma unroll
        for (int ks = 0; ks < 2; ks++) {
            bf16x8 pf[2], vf[4];
            int swz = ((ks * 4 + lq) ^ (lr & 7)) * 8;
#pragma unroll
            for (int nj = 0; nj < 2; nj++)
                pf[nj] = ldfrag(&sPw[(nj * 16 + lr) * 64 + swz]);
#pragma unroll
            for (int nd = 0; nd < 4; nd++)
                vf[nd] = ldfrag(&sv[(nd * 16 + lr) * 64 + swz]);
#pragma unroll
            for (int nj = 0; nj < 2; nj++)
#pragma unroll
                for (int nd = 0; nd < 4; nd++)
                    cacc[nj][nd] = __builtin_amdgcn_mfma_f32_16x16x32_bf16(
                        pf[nj], vf[nd], cacc[nj][nd], 0, 0, 0);
#pragma unroll
            for (int nj = 0; nj < 2; nj++)
                ssum[nj] = __builtin_amdgcn_mfma_f32_16x16x32_bf16(
                    pf[nj], ones, ssum[nj], 0, 0, 0);
        }

        if (k < 30) pipe_barrier<4>();
        else if (k == 30) pipe_barrier<0>();
        cur = (cur == 2) ? 0 : cur + 1;
    }

    const int b = bh >> 4, h = bh & 15;
    float inv[2][4];
#pragma unroll
    for (int nj = 0; nj < 2; nj++)
#pragma unroll
        for (int r = 0; r < 4; r++)
            inv[nj][r] = __builtin_amdgcn_rcpf(ssum[nj][r]);
#pragma unroll
    for (int nj = 0; nj < 2; nj++)
#pragma unroll
        for (int nd = 0; nd < 4; nd++)
#pragma unroll
            for (int r = 0; r < 4; r++) {
                int qrow = q0 + wave * 32 + nj * 16 + lq * 4 + r;
                int d = nd * 16 + lr;
                float v = cacc[nj][nd][r] * inv[nj][r];
                ctx[(size_t)(b * S_LEN + qrow) * D_MODEL + h * DK + d] = f2bf(v);
            }
}

// ---------------- launch ----------------

extern "C" void kernel_launch(void* const* d_in, const int* in_sizes, int n_in,
                              void* d_out, int out_size, void* d_ws, size_t ws_size,
                              hipStream_t stream) {
    const float* x  = (const float*)d_in[0];
    const float* Wq = (const float*)d_in[1];
    const float* bq = (const float*)d_in[2];
    const float* Wk = (const float*)d_in[3];
    const float* bk = (const float*)d_in[4];
    const float* Wv = (const float*)d_in[5];
    const float* bv = (const float*)d_in[6];
    const float* Wo = (const float*)d_in[7];
    const float* bo = (const float*)d_in[8];

    char* ws = (char*)d_ws;
    ushort* xb    = (ushort*)(ws);                        // 8 MB
    ushort* wqkv  = (ushort*)(ws + (8ull  << 20));        // 6 MB (B^T)
    ushort* wo_t  = (ushort*)(ws + (14ull << 20));        // 2 MB (B^T)
    ushort* qbuf  = (ushort*)(ws + (16ull << 20));        // 8 MB [32][2048][64]
    ushort* kbuf  = (ushort*)(ws + (24ull << 20));        // 8 MB [32][2048][64]
    ushort* vtb   = (ushort*)(ws + (32ull << 20));        // 8 MB [32][64][2048]
    ushort* ctx   = (ushort*)(ws + (40ull << 20));        // 8 MB [4096][1024]
    float*  biasq = (float*)(ws + (48ull << 20));         // 12 KB [3072]

    cvt_x_kernel<<<4096, 256, 0, stream>>>(x, xb);
    transpose_cvt4_kernel<<<dim3(32, 32, 4), dim3(32, 8), 0, stream>>>(
        Wq, Wk, Wv, Wo, wqkv, wqkv + 1024 * 1024, wqkv + 2 * 1024 * 1024, wo_t);
    cvt_bias_kernel<<<12, 256, 0, stream>>>(bq, bk, bv, biasq);

    gemm_kernel<0><<<768, 256, 0, stream>>>(
        xb, wqkv, biasq, qbuf, kbuf, vtb, nullptr, nullptr);
    attn_kernel<<<512, 256, 0, stream>>>(qbuf, kbuf, vtb, ctx);
    gemm_kernel<1><<<512, 256, 0, stream>>>(
        ctx, wo_t, bo, nullptr, nullptr, nullptr, x, (float*)d_out);
}